// Round 9
// baseline (691.322 us; speedup 1.0000x reference)
//
#include <hip/hip_runtime.h>
#include <stdint.h>

#define B_ 2
#define C_ 64
#define T_ 3000
#define F_ 65
#define H_ 4
#define D_ 4
#define E_ 16
#define TF_ (T_*F_)          // 195000
#define NPT (B_*TF_)         // 390000
#define EF 1040              // E*F
#define TP 3072              // padded T for GEMM row/col blocks
#define TK 3008              // padded key dim for Vt (47*64)
#define DQK 260              // D*F (live Q/K cols)
#define SQK 328              // Q/K global row stride
#define VTROWS 1152          // padded V cols (9*128)
#define ABUF 8192            // elems per LDS A buffer (256*32)
#define BBUF 4096            // elems per LDS B buffer (128*32)

typedef unsigned short u16;
typedef unsigned int   u32;
typedef __attribute__((ext_vector_type(8))) short  s16x8;
typedef __attribute__((ext_vector_type(4))) float  f32x4;
typedef __attribute__((ext_vector_type(4))) u32    u32x4;

__device__ __forceinline__ float bf2f(u16 u){ return __uint_as_float(((u32)u)<<16); }
__device__ __forceinline__ float bf2f_lo(u32 u){ return __uint_as_float(u<<16); }
__device__ __forceinline__ float bf2f_hi(u32 u){ return __uint_as_float(u & 0xffff0000u); }
__device__ __forceinline__ u16 f2bf(float f){
  u32 u = __float_as_uint(f);
  u32 r = u + 0x7fffu + ((u>>16)&1u);   // RNE
  return (u16)(r>>16);
}

__device__ __forceinline__ void gld16(const u16* g, u16* l){
  __builtin_amdgcn_global_load_lds((const __attribute__((address_space(1))) u32*)g,
                                   (__attribute__((address_space(3))) u32*)l,
                                   16, 0, 0);
}

// ---------------------------------------------------------------------------
// K1: per-head 1x1 conv Q/K/V + PReLU + channel-LN, via MFMA.
// ROW ORDERINGS (free permutations -- scores contracts over the whole row,
// gcol is an opaque label through vtrans/pv/Og/outp):
//   Qf/Kf row k-index = f*4+d  -> lane stores 4 d's as ONE 8B packed store,
//     16 consecutive-f lanes = 128B contiguous (was 4x 2B at 130B stride).
//   Vf row index = f*16+e      -> lane stores its 4 e's as ONE 8B store;
//     wave covers a contiguous 512B span (was 16x 2B at 130B stride).
// Fixes qkv's 1.7x HBM write amplification (140MB vs 82MB payload, round 8).
// ---------------------------------------------------------------------------
__global__ __launch_bounds__(256) void qkv_kernel(
    const float* __restrict__ x,
    const float* __restrict__ Wq, const float* __restrict__ bq, const float* __restrict__ aq,
    const float* __restrict__ gq, const float* __restrict__ bteq,
    const float* __restrict__ Wk, const float* __restrict__ bk, const float* __restrict__ ak,
    const float* __restrict__ gk, const float* __restrict__ btek,
    const float* __restrict__ Wv, const float* __restrict__ bv, const float* __restrict__ av,
    const float* __restrict__ gv, const float* __restrict__ btev,
    u16* __restrict__ Qf, u16* __restrict__ Kf, u16* __restrict__ Vf,
    float* __restrict__ lbuf)
{
  __shared__ __align__(16) u16 wlds[2*96*64];   // Whi[96][64] | Wlo[96][64], swizzled
  const int tid = threadIdx.x;
  for (int i = tid; i < 6144; i += 256){
    const int row = i >> 6, c = i & 63;
    float w;
    if (row < 16)      w = Wq[row*64 + c];
    else if (row < 32) w = Wk[(row-16)*64 + c];
    else               w = Wv[(row-32)*64 + c];
    const u16 hi = f2bf(w);
    const u16 lo = f2bf(w - bf2f(hi));
    const int byo = ((row<<7) + (c<<1)) ^ ((row&7)<<4);
    *(u16*)((char*)wlds + byo)         = hi;
    *(u16*)((char*)wlds + 12288 + byo) = lo;
  }
  const int gid = blockIdx.x*256 + tid;
  if (gid < 8*TP) lbuf[gid] = 0.f;   // zero softmax-denominator accumulator
  __syncthreads();

  const int wv_ = tid >> 6, l = tid & 63;
  const int lm = l & 15, lq = l >> 4;
  const int p0 = blockIdx.x*128 + wv_*32;     // wave's 32-point chunk

  int bb[2], rr[2]; bool ok[2];
  #pragma unroll
  for (int nt=0; nt<2; nt++){
    int p = p0 + nt*16 + lm;
    ok[nt] = (p < NPT);
    if (p >= NPT) p = NPT-1;
    bb[nt] = (p >= TF_) ? 1 : 0;
    rr[nt] = p - bb[nt]*TF_;
  }

  f32x4 acc[6][2];
  #pragma unroll
  for (int i=0;i<6;i++){
    acc[i][0]=(f32x4){0.f,0.f,0.f,0.f};
    acc[i][1]=(f32x4){0.f,0.f,0.f,0.f};
  }

  #pragma unroll
  for (int ks=0; ks<2; ks++){
    const int c0 = ks*32 + lq*8;              // this lane's 8-chan k-chunk
    s16x8 xhi[2], xlo[2];
    #pragma unroll
    for (int nt=0; nt<2; nt++){
      const float* xb = x + ((size_t)bb[nt]*C_ + c0)*TF_ + rr[nt];
      float xr[8];
      #pragma unroll
      for (int j=0;j<8;j++) xr[j] = xb[(size_t)j*TF_];
      u32x4 hw, lw;
      #pragma unroll
      for (int jw=0;jw<4;jw++){
        const u16 h0 = f2bf(xr[jw*2+0]);
        const u16 h1 = f2bf(xr[jw*2+1]);
        const float r0 = xr[jw*2+0] - bf2f(h0);
        const float r1 = xr[jw*2+1] - bf2f(h1);
        hw[jw] = (u32)h0 | ((u32)h1<<16);
        lw[jw] = (u32)f2bf(r0) | ((u32)f2bf(r1)<<16);
      }
      xhi[nt] = __builtin_bit_cast(s16x8, hw);
      xlo[nt] = __builtin_bit_cast(s16x8, lw);
    }
    #pragma unroll
    for (int mt=0; mt<6; mt++){
      const int rowb = mt*16 + lm;
      const int byo = ((rowb<<7) + (c0<<1)) ^ ((rowb&7)<<4);
      const s16x8 whi = *(const s16x8*)((const char*)wlds + byo);
      const s16x8 wlo = *(const s16x8*)((const char*)wlds + 12288 + byo);
      #pragma unroll
      for (int nt=0; nt<2; nt++){
        acc[mt][nt] = __builtin_amdgcn_mfma_f32_16x16x32_bf16(whi, xhi[nt], acc[mt][nt], 0,0,0);
        acc[mt][nt] = __builtin_amdgcn_mfma_f32_16x16x32_bf16(whi, xlo[nt], acc[mt][nt], 0,0,0);
        acc[mt][nt] = __builtin_amdgcn_mfma_f32_16x16x32_bf16(wlo, xhi[nt], acc[mt][nt], 0,0,0);
      }
    }
  }

  // epilogue: bias + PReLU + LN + packed coalesced stores
  #pragma unroll
  for (int nt=0; nt<2; nt++){
    if (!ok[nt]) continue;                       // uniform across {l,l^16,l^32,l^48}
    const int b = bb[nt], r = rr[nt];
    const u32 t = (u32)(((unsigned long long)r * 516223ULL) >> 25);   // r/65 exact
    const int f = r - (int)t*65;
    { // Q (Mtile 0): head h = lq, d = reg; LN lane-local; row k-index f*4+d
      const int h = lq;
      const float a_ = aq[h];
      float v[4]; float s1 = 0.f;
      #pragma unroll
      for (int d=0; d<4; d++){
        float a = acc[0][nt][d] + bq[h*4+d];
        a = (a >= 0.f) ? a : a_*a;
        v[d] = a; s1 += a;
      }
      const float mu = s1*0.25f;
      float var = 0.f;
      #pragma unroll
      for (int d=0; d<4; d++){ const float dd = v[d]-mu; var = fmaf(dd,dd,var); }
      var *= 0.25f;
      const float rs = rsqrtf(var + 1e-5f);
      u16 o[4];
      #pragma unroll
      for (int d=0; d<4; d++)
        o[d] = f2bf((v[d]-mu)*rs*gq[h*4+d] + bteq[h*4+d]);
      const u32 lo = (u32)o[0] | ((u32)o[1]<<16);
      const u32 hi = (u32)o[2] | ((u32)o[3]<<16);
      *(uint2*)(Qf + ((size_t)(b*4+h)*TP + t)*SQK + f*4) = make_uint2(lo, hi);
    }
    { // K (Mtile 1)
      const int h = lq;
      const float a_ = ak[h];
      float v[4]; float s1 = 0.f;
      #pragma unroll
      for (int d=0; d<4; d++){
        float a = acc[1][nt][d] + bk[h*4+d];
        a = (a >= 0.f) ? a : a_*a;
        v[d] = a; s1 += a;
      }
      const float mu = s1*0.25f;
      float var = 0.f;
      #pragma unroll
      for (int d=0; d<4; d++){ const float dd = v[d]-mu; var = fmaf(dd,dd,var); }
      var *= 0.25f;
      const float rs = rsqrtf(var + 1e-5f);
      u16 o[4];
      #pragma unroll
      for (int d=0; d<4; d++)
        o[d] = f2bf((v[d]-mu)*rs*gk[h*4+d] + btek[h*4+d]);
      const u32 lo = (u32)o[0] | ((u32)o[1]<<16);
      const u32 hi = (u32)o[2] | ((u32)o[3]<<16);
      *(uint2*)(Kf + ((size_t)(b*4+h)*TP + t)*SQK + f*4) = make_uint2(lo, hi);
    }
    // zero the K-padding cols 260..287 of Qf/Kf for this (bh,t) row
    if (f < 28) {
      #pragma unroll
      for (int h2=0; h2<4; h2++){
        Qf[((size_t)(b*4+h2)*TP + t)*SQK + 260 + f] = 0;
        Kf[((size_t)(b*4+h2)*TP + t)*SQK + 260 + f] = 0;
      }
    }
    // V (Mtiles 2..5): head h = mt-2, e = lq*4+reg; LN over 16 via quarters.
    // Row gcol-index f*16+e -> one 8B store per lane (wave tiles 512B).
    #pragma unroll
    for (int mt=2; mt<6; mt++){
      const int h = mt-2;
      const float a_ = av[h];
      float v[4]; float s1 = 0.f, s2 = 0.f;
      #pragma unroll
      for (int e4=0; e4<4; e4++){
        float a = acc[mt][nt][e4] + bv[h*16 + lq*4 + e4];
        a = (a >= 0.f) ? a : a_*a;
        v[e4] = a; s1 += a; s2 = fmaf(a,a,s2);
      }
      s1 += __shfl_xor(s1,16); s1 += __shfl_xor(s1,32);
      s2 += __shfl_xor(s2,16); s2 += __shfl_xor(s2,32);
      const float mu = s1*(1.f/16.f);
      const float var = s2*(1.f/16.f) - mu*mu;
      const float rs = rsqrtf(var + 1e-5f);
      u16 o[4];
      #pragma unroll
      for (int e4=0; e4<4; e4++){
        const int e = lq*4 + e4;
        o[e4] = f2bf((v[e4]-mu)*rs*gv[h*16+e] + btev[h*16+e]);
      }
      const u32 lo = (u32)o[0] | ((u32)o[1]<<16);
      const u32 hi = (u32)o[2] | ((u32)o[3]<<16);
      *(uint2*)(Vf + ((size_t)(b*4+h)*T_ + t)*EF + f*16 + lq*4) = make_uint2(lo, hi);
    }
  }
}

// ---------------------------------------------------------------------------
// K2: transpose V -> Vt [8][1152][3008] bf16 (keys>=3000 and cols>=1040 -> 0)
// (gcol is an opaque label; code identical under the new Vf row ordering)
// ---------------------------------------------------------------------------
__global__ __launch_bounds__(256) void vtrans_kernel(
    const u16* __restrict__ Vf, u16* __restrict__ Vt)
{
  __shared__ u16 tile[64][68];
  const int bh = blockIdx.z, t0 = blockIdx.x*64, c0 = blockIdx.y*64;
  const int tid = threadIdx.x;
  const int rr = tid>>4, cc4 = (tid&15)*4;
  #pragma unroll
  for (int i=0;i<4;i++){
    const int key = t0 + rr + i*16;
    ushort4 v = {0,0,0,0};
    if (key < T_) {
      const u16* src = Vf + ((size_t)bh*T_ + key)*EF + c0 + cc4;
      if (c0 + cc4 + 3 < EF) v = *(const ushort4*)src;
      else {
        if (c0+cc4+0 < EF) v.x = src[0];
        if (c0+cc4+1 < EF) v.y = src[1];
        if (c0+cc4+2 < EF) v.z = src[2];
        if (c0+cc4+3 < EF) v.w = src[3];
      }
    }
    *(ushort4*)&tile[rr + i*16][cc4] = v;
  }
  __syncthreads();
  #pragma unroll
  for (int i=0;i<4;i++){
    const int cl = rr + i*16;
    const int col = c0 + cl;
    ushort4 v;
    v.x = tile[cc4+0][cl];
    v.y = tile[cc4+1][cl];
    v.z = tile[cc4+2][cl];
    v.w = tile[cc4+3][cl];
    *(ushort4*)(Vt + ((size_t)bh*VTROWS + col)*TK + t0 + cc4) = v;
  }
}

// ---------------------------------------------------------------------------
// shared GEMM core: C(256x128) += A(256xK) * B(128xK)^T, bf16, 8 waves,
// 3-deep LDS pipeline, counted vmcnt (round-7, verified).
// ---------------------------------------------------------------------------
__device__ __forceinline__ void gemm_core(
    const u16* __restrict__ Ag, const u16* __restrict__ Bg,
    size_t strideA, size_t strideB, int niter,
    u16* As, u16* Bs, f32x4 acc[4][4], int w, int l, int tid)
{
  const int sa1 = tid + 512;
  const int ra0 = tid>>2, ja0 = (tid&3) ^ ((ra0>>1)&3);
  const int ra1 = sa1>>2, ja1 = (sa1&3) ^ ((ra1>>1)&3);
  const int jb0 = (tid&3) ^ ((ra0>>1)&3);     // B row = tid>>2 (128 rows)
  const u16* gA0 = Ag + (size_t)ra0*strideA + ja0*8;
  const u16* gA1 = Ag + (size_t)ra1*strideA + ja1*8;
  const u16* gB0 = Bg + (size_t)ra0*strideB + jb0*8;
  u16* lA0 = As + (size_t)(w*64)*8;           // wave-uniform base; lane scatter
  u16* lA1 = As + (size_t)(512 + w*64)*8;
  u16* lB0 = Bs + (size_t)(w*64)*8;
  const int m = l & 15, q = l >> 4;
  const int sw = (q ^ ((m>>1)&3)) << 3;       // swizzled chunk slot offset (elems)
  const int ra = (w&3)*64 + m;
  const int rb = (w>>2)*64 + m;

  #pragma unroll
  for (int t=0; t<3; ++t){
    if (t < niter){
      const int k0 = t*32;
      gld16(gA0 + k0, lA0 + t*ABUF);
      gld16(gA1 + k0, lA1 + t*ABUF);
      gld16(gB0 + k0, lB0 + t*BBUF);
    }
  }
  int cur = 0;
  for (int it = 0; it < niter; ++it) {
    if (it < niter-2)      asm volatile("s_waitcnt vmcnt(6)" ::: "memory");
    else if (it < niter-1) asm volatile("s_waitcnt vmcnt(3)" ::: "memory");
    else                   asm volatile("s_waitcnt vmcnt(0)" ::: "memory");
    __builtin_amdgcn_s_barrier();
    __builtin_amdgcn_sched_barrier(0);
    s16x8 a[4], b[4];
    #pragma unroll
    for (int i=0;i<4;i++) a[i] = *(const s16x8*)(As + cur*ABUF + (ra + i*16)*32 + sw);
    #pragma unroll
    for (int j=0;j<4;j++) b[j] = *(const s16x8*)(Bs + cur*BBUF + (rb + j*16)*32 + sw);
    #pragma unroll
    for (int i=0;i<4;i++)
      #pragma unroll
      for (int j=0;j<4;j++)
        acc[i][j] = __builtin_amdgcn_mfma_f32_16x16x32_bf16(a[i], b[j], acc[i][j], 0, 0, 0);
    __builtin_amdgcn_sched_barrier(0);
    __builtin_amdgcn_s_barrier();
    if (it + 3 < niter) {             // re-stage into the buffer just freed
      const int k0 = (it+3)*32;
      gld16(gA0 + k0, lA0 + cur*ABUF);
      gld16(gA1 + k0, lA1 + cur*ABUF);
      gld16(gB0 + k0, lB0 + cur*BBUF);
    }
    cur = (cur == 2) ? 0 : cur + 1;
  }
}

// ---------------------------------------------------------------------------
// K3: scores, operand-SWAPPED: A = K (gcol dim, 256-tile), B = Q (grow dim,
// 128-tile). Each lane gets 4 consecutive gcols of one row -> packed 8B
// stores. P~ = exp(scale*QK^T) bf16 [z][3072][3072] row-major.
// ---------------------------------------------------------------------------
__global__ __launch_bounds__(512) void scores_kernel(
    const u16* __restrict__ Qf, const u16* __restrict__ Kf,
    u16* __restrict__ P, float* __restrict__ lbuf, int bh0)
{
  __shared__ __align__(16) u16 As[3*ABUF];   // 48 KB
  __shared__ __align__(16) u16 Bs[3*BBUF];   // 24 KB
  const int tid = threadIdx.x, w = tid>>6, l = tid&63;
  const int bh = bh0 + blockIdx.z;
  const int gcol0 = blockIdx.x*256, row0 = blockIdx.y*128;
  const u16* Ag = Kf + ((size_t)bh*TP + gcol0)*SQK;   // A = K
  const u16* Bg = Qf + ((size_t)bh*TP + row0)*SQK;    // B = Q

  f32x4 acc[4][4];
  #pragma unroll
  for (int i=0;i<4;i++)
    #pragma unroll
    for (int j=0;j<4;j++) acc[i][j] = (f32x4){0.f,0.f,0.f,0.f};

  gemm_core(Ag, Bg, SQK, SQK, 9, As, Bs, acc, w, l, tid);

  const float scale = 0.062017367294604234f;   // 1/sqrt(260)
  const int m = l & 15, q = l >> 4;
  u16* Pz = P + (size_t)blockIdx.z*TP*TP;
  float* lrow = lbuf + (size_t)bh*TP;

  float rsum[4] = {0.f,0.f,0.f,0.f};
  #pragma unroll
  for (int i=0;i<4;i++){
    const int gcb = gcol0 + (w&3)*64 + i*16 + q*4;   // 4 consecutive gcols
    #pragma unroll
    for (int j=0;j<4;j++){
      const int grow = row0 + (w>>2)*64 + j*16 + m;
      float pv[4];
      #pragma unroll
      for (int reg=0; reg<4; reg++){
        float v = __expf(acc[i][j][reg]*scale);
        if (gcb + reg >= T_) v = 0.f;
        pv[reg] = v; rsum[j] += v;
      }
      const u32 lo = (u32)f2bf(pv[0]) | ((u32)f2bf(pv[1])<<16);
      const u32 hi = (u32)f2bf(pv[2]) | ((u32)f2bf(pv[3])<<16);
      *(uint2*)(Pz + (size_t)grow*TP + gcb) = make_uint2(lo, hi);
    }
  }
  #pragma unroll
  for (int j=0;j<4;j++){
    float r = rsum[j];
    r += __shfl_xor(r, 16);
    r += __shfl_xor(r, 32);
    if (q == 0) atomicAdd(&lrow[row0 + (w>>2)*64 + j*16 + m], r);
  }
}

// ---------------------------------------------------------------------------
// K4: O = (P~ * V) / l  -> Og bf16 [bh][t][gcol]  (gcol-contiguous, coalesced)
// ---------------------------------------------------------------------------
__global__ __launch_bounds__(512) void pv_kernel(
    const u16* __restrict__ P, const u16* __restrict__ Vt,
    const float* __restrict__ lbuf, u16* __restrict__ Og, int bh0)
{
  __shared__ __align__(16) u16 As[3*ABUF];
  __shared__ __align__(16) u16 Bs[3*BBUF];
  const int tid = threadIdx.x, w = tid>>6, l = tid&63;
  const int bh = bh0 + blockIdx.z;
  const int row0 = blockIdx.x*256, col0 = blockIdx.y*128;
  const u16* Ag = P + (size_t)blockIdx.z*TP*TP + (size_t)row0*TP;
  const u16* Bg = Vt + ((size_t)bh*VTROWS + col0)*TK;

  f32x4 acc[4][4];
  #pragma unroll
  for (int i=0;i<4;i++)
    #pragma unroll
    for (int j=0;j<4;j++) acc[i][j] = (f32x4){0.f,0.f,0.f,0.f};

  gemm_core(Ag, Bg, TP, TK, 94, As, Bs, acc, w, l, tid);

  const int m = l & 15, q = l >> 4;
  const float* lrow = lbuf + (size_t)bh*TP;

  #pragma unroll
  for (int i=0;i<4;i++){
    #pragma unroll
    for (int reg=0; reg<4; reg++){
      const int grow = row0 + (w&3)*64 + i*16 + q*4 + reg;
      if (grow >= T_) continue;
      const float linv = 1.0f / lrow[grow];
      u16* orow = Og + ((size_t)bh*T_ + grow)*EF;
      #pragma unroll
      for (int j=0;j<4;j++){
        const int gcol = col0 + (w>>2)*64 + j*16 + m;
        if (gcol < EF)
          orow[gcol] = f2bf(acc[i][j][reg]*linv);
      }
    }
  }
}

// ---------------------------------------------------------------------------
// K5: final 1x1 conv (64x64) + PReLU + LN over C + residual, MFMA-style.
// With Og gcol = f*16+e, the fragment gather is ONE aligned 16B load
// (8 consecutive u16) instead of 8x 2B strided loads.
// ---------------------------------------------------------------------------
__global__ __launch_bounds__(256) void outp_kernel(
    const u16* __restrict__ Og, const float* __restrict__ x,
    const float* __restrict__ Wp, const float* __restrict__ bp, const float* __restrict__ ap,
    const float* __restrict__ gp, const float* __restrict__ btep,
    float* __restrict__ out)
{
  __shared__ __align__(16) u16 wlds[2*64*64];   // Whi | Wlo, swizzled (16 KB)
  __shared__ float prm[193];
  const int tid = threadIdx.x;
  for (int i = tid; i < 4096; i += 256){
    const int row = i >> 6, c = i & 63;
    const float w = Wp[row*64 + c];
    const u16 hi = f2bf(w);
    const u16 lo = f2bf(w - bf2f(hi));
    const int byo = ((row<<7) + (c<<1)) ^ ((row&7)<<4);
    *(u16*)((char*)wlds + byo)        = hi;
    *(u16*)((char*)wlds + 8192 + byo) = lo;
  }
  if (tid < 193) {
    float v;
    if      (tid < 64)  v = bp[tid];
    else if (tid < 128) v = gp[tid-64];
    else if (tid < 192) v = btep[tid-128];
    else                v = ap[0];
    prm[tid] = v;
  }
  __syncthreads();

  const int wv_ = tid >> 6, l = tid & 63;
  const int lm = l & 15, lq = l >> 4;
  const int p0 = blockIdx.x*128 + wv_*32;

  int bb[2], rr[2], tt[2], ff[2]; bool ok[2];
  #pragma unroll
  for (int nt=0; nt<2; nt++){
    int p = p0 + nt*16 + lm;
    ok[nt] = (p < NPT);
    if (p >= NPT) p = NPT-1;
    bb[nt] = (p >= TF_) ? 1 : 0;
    rr[nt] = p - bb[nt]*TF_;
    tt[nt] = (int)(((unsigned long long)rr[nt] * 516223ULL) >> 25);   // r/65 exact
    ff[nt] = rr[nt] - tt[nt]*65;
  }

  f32x4 acc[4][2];
  #pragma unroll
  for (int i=0;i<4;i++){
    acc[i][0]=(f32x4){0.f,0.f,0.f,0.f};
    acc[i][1]=(f32x4){0.f,0.f,0.f,0.f};
  }

  #pragma unroll
  for (int ks=0; ks<2; ks++){
    const int c0 = ks*32 + lq*8;        // 8 input channels, h uniform in chunk
    const int h  = c0 >> 4;
    const int e0 = c0 & 15;
    s16x8 xf[2];
    #pragma unroll
    for (int nt=0; nt<2; nt++){
      const u16* base = Og + ((size_t)(bb[nt]*4 + h)*T_ + tt[nt])*EF + ff[nt]*16 + e0;
      xf[nt] = *(const s16x8*)base;     // 16B aligned: row stride 2080B, f*32+e0*2
    }
    #pragma unroll
    for (int mt=0; mt<4; mt++){
      const int rowb = mt*16 + lm;
      const int byo = ((rowb<<7) + (c0<<1)) ^ ((rowb&7)<<4);
      const s16x8 whi = *(const s16x8*)((const char*)wlds + byo);
      const s16x8 wlo = *(const s16x8*)((const char*)wlds + 8192 + byo);
      #pragma unroll
      for (int nt=0; nt<2; nt++){
        acc[mt][nt] = __builtin_amdgcn_mfma_f32_16x16x32_bf16(whi, xf[nt], acc[mt][nt], 0,0,0);
        acc[mt][nt] = __builtin_amdgcn_mfma_f32_16x16x32_bf16(wlo, xf[nt], acc[mt][nt], 0,0,0);
      }
    }
  }

  const float apv = prm[192];
  #pragma unroll
  for (int nt=0; nt<2; nt++){
    if (!ok[nt]) continue;              // uniform across {l, l^16, l^32, l^48}
    const int b = bb[nt], r = rr[nt];
    float v[4][4]; float s1 = 0.f, s2 = 0.f;
    #pragma unroll
    for (int mt=0; mt<4; mt++){
      #pragma unroll
      for (int reg=0; reg<4; reg++){
        const int o = mt*16 + lq*4 + reg;
        float a = acc[mt][nt][reg] + prm[o];
        a = (a >= 0.f) ? a : apv*a;
        v[mt][reg] = a; s1 += a; s2 = fmaf(a,a,s2);
      }
    }
    s1 += __shfl_xor(s1,16); s1 += __shfl_xor(s1,32);
    s2 += __shfl_xor(s2,16); s2 += __shfl_xor(s2,32);
    const float mu = s1*(1.f/64.f);
    const float var = s2*(1.f/64.f) - mu*mu;
    const float rs = rsqrtf(var + 1e-5f);
    const float* xb = x + (size_t)b*C_*TF_ + r;
    float* yb = out + (size_t)b*C_*TF_ + r;
    #pragma unroll
    for (int mt=0; mt<4; mt++){
      #pragma unroll
      for (int reg=0; reg<4; reg++){
        const int o = mt*16 + lq*4 + reg;
        yb[(size_t)o*TF_] = fmaf((v[mt][reg]-mu)*rs, prm[64+o], prm[128+o]) + xb[(size_t)o*TF_];
      }
    }
  }
}

// ---------------------------------------------------------------------------
extern "C" void kernel_launch(void* const* d_in, const int* in_sizes, int n_in,
                              void* d_out, int out_size, void* d_ws, size_t ws_size,
                              hipStream_t stream)
{
  const float* x    = (const float*)d_in[0];
  const float* Wq   = (const float*)d_in[1];
  const float* bq   = (const float*)d_in[2];
  const float* aq   = (const float*)d_in[3];
  const float* gq   = (const float*)d_in[4];
  const float* bteq = (const float*)d_in[5];
  const float* Wk   = (const float*)d_in[6];
  const float* bk   = (const float*)d_in[7];
  const float* ak   = (const float*)d_in[8];
  const float* gk   = (const float*)d_in[9];
  const float* btek = (const float*)d_in[10];
  const float* Wv   = (const float*)d_in[11];
  const float* bv   = (const float*)d_in[12];
  const float* av   = (const float*)d_in[13];
  const float* gv   = (const float*)d_in[14];
  const float* btev = (const float*)d_in[15];
  const float* Wp   = (const float*)d_in[16];
  const float* bp   = (const float*)d_in[17];
  const float* ap   = (const float*)d_in[18];
  const float* gp   = (const float*)d_in[19];
  const float* btep = (const float*)d_in[20];

  // workspace layout (bytes):
  //   Qf   bf16 [8][3072][328]   @ 0            (16,121,856)
  //   Kf   bf16 [8][3072][328]   @ 16,121,856   (16,121,856)
  //   Vf   bf16 [8][3000][1040]  @ 32,243,712   (49,920,000)  -- dead after vtrans
  //   Og   bf16 [8][3000][1040]  @ 32,243,712   (49,920,000)  -- overlays Vf
  //   Vt   bf16 [8][1152][3008]  @ 82,163,712   (55,443,456)
  // z=4 layout (needs 213,202,944 B):
  //   lbuf f32  [8][3072]        @ 137,607,168  (98,304)
  //   P    bf16 [4][3072][3072]  @ 137,705,472  (75,497,472)
  // z=2 fallback (old layout, 175,454,208 B):
  //   P    bf16 [2][3072][3072]  @ 137,607,168  (37,748,736)
  //   lbuf f32  [8][3072]        @ 175,355,904  (98,304)
  char* ws = (char*)d_ws;
  u16*   Qf   = (u16*)(ws + 0);
  u16*   Kf   = (u16*)(ws + 16121856);
  u16*   Vf   = (u16*)(ws + 32243712);
  u16*   Og   = (u16*)(ws + 32243712);
  u16*   Vt   = (u16*)(ws + 82163712);
  const bool z4 = (ws_size >= (size_t)213202944);
  u16*   P;
  float* lbuf;
  if (z4) { lbuf = (float*)(ws + 137607168); P = (u16*)(ws + 137705472); }
  else    { P = (u16*)(ws + 137607168);      lbuf = (float*)(ws + 175355904); }
  float* out  = (float*)d_out;

  qkv_kernel<<<dim3((NPT+127)/128), dim3(256), 0, stream>>>(
      x, Wq,bq,aq,gq,bteq, Wk,bk,ak,gk,btek, Wv,bv,av,gv,btev, Qf,Kf,Vf, lbuf);
  vtrans_kernel<<<dim3(47, 17, 8), dim3(256), 0, stream>>>(Vf, Vt);
  if (z4) {
    for (int c = 0; c < 2; ++c) {
      scores_kernel<<<dim3(12, 24, 4), dim3(512), 0, stream>>>(Qf, Kf, P, lbuf, c*4);
      pv_kernel<<<dim3(12, 9, 4), dim3(512), 0, stream>>>(P, Vt, lbuf, Og, c*4);
    }
  } else {
    for (int c = 0; c < 4; ++c) {
      scores_kernel<<<dim3(12, 24, 2), dim3(512), 0, stream>>>(Qf, Kf, P, lbuf, c*2);
      pv_kernel<<<dim3(12, 9, 2), dim3(512), 0, stream>>>(P, Vt, lbuf, Og, c*2);
    }
  }
  outp_kernel<<<dim3((NPT+127)/128), dim3(256), 0, stream>>>(
      Og, x, Wp,bp,ap,gp,btep, out);
}

// Round 10
// 680.055 us; speedup vs baseline: 1.0166x; 1.0166x over previous
//
#include <hip/hip_runtime.h>
#include <stdint.h>

#define B_ 2
#define C_ 64
#define T_ 3000
#define F_ 65
#define H_ 4
#define D_ 4
#define E_ 16
#define TF_ (T_*F_)          // 195000
#define NPT (B_*TF_)         // 390000
#define EF 1040              // E*F
#define TP 3072              // padded T for GEMM row/col blocks
#define TK 3008              // padded key dim for Vt (47*64)
#define DQK 260              // D*F (live Q/K cols)
#define SQK 328              // Q/K global row stride
#define VTROWS 1152          // padded V cols (9*128)
#define ABUF 8192            // elems per LDS A buffer (256*32)
#define BBUF 4096            // elems per LDS B buffer (128*32)

typedef unsigned short u16;
typedef unsigned int   u32;
typedef __attribute__((ext_vector_type(8))) short  s16x8;
typedef __attribute__((ext_vector_type(4))) float  f32x4;
typedef __attribute__((ext_vector_type(4))) u32    u32x4;

__device__ __forceinline__ float bf2f(u16 u){ return __uint_as_float(((u32)u)<<16); }
__device__ __forceinline__ float bf2f_lo(u32 u){ return __uint_as_float(u<<16); }
__device__ __forceinline__ float bf2f_hi(u32 u){ return __uint_as_float(u & 0xffff0000u); }
__device__ __forceinline__ u16 f2bf(float f){
  u32 u = __float_as_uint(f);
  u32 r = u + 0x7fffu + ((u>>16)&1u);   // RNE
  return (u16)(r>>16);
}

__device__ __forceinline__ void gld16(const u16* g, u16* l){
  __builtin_amdgcn_global_load_lds((const __attribute__((address_space(1))) u32*)g,
                                   (__attribute__((address_space(3))) u32*)l,
                                   16, 0, 0);
}

// ---------------------------------------------------------------------------
// K1: per-head 1x1 conv Q/K/V + PReLU + channel-LN, via MFMA.
// Row orderings: Qf/Kf k-index = f*4+d; Vf gcol = f*16+e (packed 8B stores).
// ---------------------------------------------------------------------------
__global__ __launch_bounds__(256) void qkv_kernel(
    const float* __restrict__ x,
    const float* __restrict__ Wq, const float* __restrict__ bq, const float* __restrict__ aq,
    const float* __restrict__ gq, const float* __restrict__ bteq,
    const float* __restrict__ Wk, const float* __restrict__ bk, const float* __restrict__ ak,
    const float* __restrict__ gk, const float* __restrict__ btek,
    const float* __restrict__ Wv, const float* __restrict__ bv, const float* __restrict__ av,
    const float* __restrict__ gv, const float* __restrict__ btev,
    u16* __restrict__ Qf, u16* __restrict__ Kf, u16* __restrict__ Vf,
    float* __restrict__ lbuf)
{
  __shared__ __align__(16) u16 wlds[2*96*64];   // Whi[96][64] | Wlo[96][64], swizzled
  const int tid = threadIdx.x;
  for (int i = tid; i < 6144; i += 256){
    const int row = i >> 6, c = i & 63;
    float w;
    if (row < 16)      w = Wq[row*64 + c];
    else if (row < 32) w = Wk[(row-16)*64 + c];
    else               w = Wv[(row-32)*64 + c];
    const u16 hi = f2bf(w);
    const u16 lo = f2bf(w - bf2f(hi));
    const int byo = ((row<<7) + (c<<1)) ^ ((row&7)<<4);
    *(u16*)((char*)wlds + byo)         = hi;
    *(u16*)((char*)wlds + 12288 + byo) = lo;
  }
  const int gid = blockIdx.x*256 + tid;
  if (gid < 8*TP) lbuf[gid] = 0.f;   // zero softmax-denominator accumulator
  __syncthreads();

  const int wv_ = tid >> 6, l = tid & 63;
  const int lm = l & 15, lq = l >> 4;
  const int p0 = blockIdx.x*128 + wv_*32;     // wave's 32-point chunk

  int bb[2], rr[2]; bool ok[2];
  #pragma unroll
  for (int nt=0; nt<2; nt++){
    int p = p0 + nt*16 + lm;
    ok[nt] = (p < NPT);
    if (p >= NPT) p = NPT-1;
    bb[nt] = (p >= TF_) ? 1 : 0;
    rr[nt] = p - bb[nt]*TF_;
  }

  f32x4 acc[6][2];
  #pragma unroll
  for (int i=0;i<6;i++){
    acc[i][0]=(f32x4){0.f,0.f,0.f,0.f};
    acc[i][1]=(f32x4){0.f,0.f,0.f,0.f};
  }

  #pragma unroll
  for (int ks=0; ks<2; ks++){
    const int c0 = ks*32 + lq*8;              // this lane's 8-chan k-chunk
    s16x8 xhi[2], xlo[2];
    #pragma unroll
    for (int nt=0; nt<2; nt++){
      const float* xb = x + ((size_t)bb[nt]*C_ + c0)*TF_ + rr[nt];
      float xr[8];
      #pragma unroll
      for (int j=0;j<8;j++) xr[j] = xb[(size_t)j*TF_];
      u32x4 hw, lw;
      #pragma unroll
      for (int jw=0;jw<4;jw++){
        const u16 h0 = f2bf(xr[jw*2+0]);
        const u16 h1 = f2bf(xr[jw*2+1]);
        const float r0 = xr[jw*2+0] - bf2f(h0);
        const float r1 = xr[jw*2+1] - bf2f(h1);
        hw[jw] = (u32)h0 | ((u32)h1<<16);
        lw[jw] = (u32)f2bf(r0) | ((u32)f2bf(r1)<<16);
      }
      xhi[nt] = __builtin_bit_cast(s16x8, hw);
      xlo[nt] = __builtin_bit_cast(s16x8, lw);
    }
    #pragma unroll
    for (int mt=0; mt<6; mt++){
      const int rowb = mt*16 + lm;
      const int byo = ((rowb<<7) + (c0<<1)) ^ ((rowb&7)<<4);
      const s16x8 whi = *(const s16x8*)((const char*)wlds + byo);
      const s16x8 wlo = *(const s16x8*)((const char*)wlds + 12288 + byo);
      #pragma unroll
      for (int nt=0; nt<2; nt++){
        acc[mt][nt] = __builtin_amdgcn_mfma_f32_16x16x32_bf16(whi, xhi[nt], acc[mt][nt], 0,0,0);
        acc[mt][nt] = __builtin_amdgcn_mfma_f32_16x16x32_bf16(whi, xlo[nt], acc[mt][nt], 0,0,0);
        acc[mt][nt] = __builtin_amdgcn_mfma_f32_16x16x32_bf16(wlo, xhi[nt], acc[mt][nt], 0,0,0);
      }
    }
  }

  // epilogue: bias + PReLU + LN + packed coalesced stores
  #pragma unroll
  for (int nt=0; nt<2; nt++){
    if (!ok[nt]) continue;                       // uniform across {l,l^16,l^32,l^48}
    const int b = bb[nt], r = rr[nt];
    const u32 t = (u32)(((unsigned long long)r * 516223ULL) >> 25);   // r/65 exact
    const int f = r - (int)t*65;
    { // Q (Mtile 0): head h = lq, d = reg; LN lane-local; row k-index f*4+d
      const int h = lq;
      const float a_ = aq[h];
      float v[4]; float s1 = 0.f;
      #pragma unroll
      for (int d=0; d<4; d++){
        float a = acc[0][nt][d] + bq[h*4+d];
        a = (a >= 0.f) ? a : a_*a;
        v[d] = a; s1 += a;
      }
      const float mu = s1*0.25f;
      float var = 0.f;
      #pragma unroll
      for (int d=0; d<4; d++){ const float dd = v[d]-mu; var = fmaf(dd,dd,var); }
      var *= 0.25f;
      const float rs = rsqrtf(var + 1e-5f);
      u16 o[4];
      #pragma unroll
      for (int d=0; d<4; d++)
        o[d] = f2bf((v[d]-mu)*rs*gq[h*4+d] + bteq[h*4+d]);
      const u32 lo = (u32)o[0] | ((u32)o[1]<<16);
      const u32 hi = (u32)o[2] | ((u32)o[3]<<16);
      *(uint2*)(Qf + ((size_t)(b*4+h)*TP + t)*SQK + f*4) = make_uint2(lo, hi);
    }
    { // K (Mtile 1)
      const int h = lq;
      const float a_ = ak[h];
      float v[4]; float s1 = 0.f;
      #pragma unroll
      for (int d=0; d<4; d++){
        float a = acc[1][nt][d] + bk[h*4+d];
        a = (a >= 0.f) ? a : a_*a;
        v[d] = a; s1 += a;
      }
      const float mu = s1*0.25f;
      float var = 0.f;
      #pragma unroll
      for (int d=0; d<4; d++){ const float dd = v[d]-mu; var = fmaf(dd,dd,var); }
      var *= 0.25f;
      const float rs = rsqrtf(var + 1e-5f);
      u16 o[4];
      #pragma unroll
      for (int d=0; d<4; d++)
        o[d] = f2bf((v[d]-mu)*rs*gk[h*4+d] + btek[h*4+d]);
      const u32 lo = (u32)o[0] | ((u32)o[1]<<16);
      const u32 hi = (u32)o[2] | ((u32)o[3]<<16);
      *(uint2*)(Kf + ((size_t)(b*4+h)*TP + t)*SQK + f*4) = make_uint2(lo, hi);
    }
    // zero the K-padding cols 260..287 of Qf/Kf for this (bh,t) row
    if (f < 28) {
      #pragma unroll
      for (int h2=0; h2<4; h2++){
        Qf[((size_t)(b*4+h2)*TP + t)*SQK + 260 + f] = 0;
        Kf[((size_t)(b*4+h2)*TP + t)*SQK + 260 + f] = 0;
      }
    }
    // V (Mtiles 2..5): head h = mt-2, e = lq*4+reg; LN over 16 via quarters.
    #pragma unroll
    for (int mt=2; mt<6; mt++){
      const int h = mt-2;
      const float a_ = av[h];
      float v[4]; float s1 = 0.f, s2 = 0.f;
      #pragma unroll
      for (int e4=0; e4<4; e4++){
        float a = acc[mt][nt][e4] + bv[h*16 + lq*4 + e4];
        a = (a >= 0.f) ? a : a_*a;
        v[e4] = a; s1 += a; s2 = fmaf(a,a,s2);
      }
      s1 += __shfl_xor(s1,16); s1 += __shfl_xor(s1,32);
      s2 += __shfl_xor(s2,16); s2 += __shfl_xor(s2,32);
      const float mu = s1*(1.f/16.f);
      const float var = s2*(1.f/16.f) - mu*mu;
      const float rs = rsqrtf(var + 1e-5f);
      u16 o[4];
      #pragma unroll
      for (int e4=0; e4<4; e4++){
        const int e = lq*4 + e4;
        o[e4] = f2bf((v[e4]-mu)*rs*gv[h*16+e] + btev[h*16+e]);
      }
      const u32 lo = (u32)o[0] | ((u32)o[1]<<16);
      const u32 hi = (u32)o[2] | ((u32)o[3]<<16);
      *(uint2*)(Vf + ((size_t)(b*4+h)*T_ + t)*EF + f*16 + lq*4) = make_uint2(lo, hi);
    }
  }
}

// ---------------------------------------------------------------------------
// K2: transpose V -> Vt [8][1152][3008] bf16 (keys>=3000 and cols>=1040 -> 0)
// ---------------------------------------------------------------------------
__global__ __launch_bounds__(256) void vtrans_kernel(
    const u16* __restrict__ Vf, u16* __restrict__ Vt)
{
  __shared__ u16 tile[64][68];
  const int bh = blockIdx.z, t0 = blockIdx.x*64, c0 = blockIdx.y*64;
  const int tid = threadIdx.x;
  const int rr = tid>>4, cc4 = (tid&15)*4;
  #pragma unroll
  for (int i=0;i<4;i++){
    const int key = t0 + rr + i*16;
    ushort4 v = {0,0,0,0};
    if (key < T_) {
      const u16* src = Vf + ((size_t)bh*T_ + key)*EF + c0 + cc4;
      if (c0 + cc4 + 3 < EF) v = *(const ushort4*)src;
      else {
        if (c0+cc4+0 < EF) v.x = src[0];
        if (c0+cc4+1 < EF) v.y = src[1];
        if (c0+cc4+2 < EF) v.z = src[2];
        if (c0+cc4+3 < EF) v.w = src[3];
      }
    }
    *(ushort4*)&tile[rr + i*16][cc4] = v;
  }
  __syncthreads();
  #pragma unroll
  for (int i=0;i<4;i++){
    const int cl = rr + i*16;
    const int col = c0 + cl;
    ushort4 v;
    v.x = tile[cc4+0][cl];
    v.y = tile[cc4+1][cl];
    v.z = tile[cc4+2][cl];
    v.w = tile[cc4+3][cl];
    *(ushort4*)(Vt + ((size_t)bh*VTROWS + col)*TK + t0 + cc4) = v;
  }
}

// ---------------------------------------------------------------------------
// shared GEMM core: C(256x128) += A(256xK) * B(128xK)^T, bf16, 8 waves,
// 3-deep LDS pipeline, counted vmcnt (round-7, verified).
// ---------------------------------------------------------------------------
__device__ __forceinline__ void gemm_core(
    const u16* __restrict__ Ag, const u16* __restrict__ Bg,
    size_t strideA, size_t strideB, int niter,
    u16* As, u16* Bs, f32x4 acc[4][4], int w, int l, int tid)
{
  const int sa1 = tid + 512;
  const int ra0 = tid>>2, ja0 = (tid&3) ^ ((ra0>>1)&3);
  const int ra1 = sa1>>2, ja1 = (sa1&3) ^ ((ra1>>1)&3);
  const int jb0 = (tid&3) ^ ((ra0>>1)&3);     // B row = tid>>2 (128 rows)
  const u16* gA0 = Ag + (size_t)ra0*strideA + ja0*8;
  const u16* gA1 = Ag + (size_t)ra1*strideA + ja1*8;
  const u16* gB0 = Bg + (size_t)ra0*strideB + jb0*8;
  u16* lA0 = As + (size_t)(w*64)*8;           // wave-uniform base; lane scatter
  u16* lA1 = As + (size_t)(512 + w*64)*8;
  u16* lB0 = Bs + (size_t)(w*64)*8;
  const int m = l & 15, q = l >> 4;
  const int sw = (q ^ ((m>>1)&3)) << 3;       // swizzled chunk slot offset (elems)
  const int ra = (w&3)*64 + m;
  const int rb = (w>>2)*64 + m;

  #pragma unroll
  for (int t=0; t<3; ++t){
    if (t < niter){
      const int k0 = t*32;
      gld16(gA0 + k0, lA0 + t*ABUF);
      gld16(gA1 + k0, lA1 + t*ABUF);
      gld16(gB0 + k0, lB0 + t*BBUF);
    }
  }
  int cur = 0;
  for (int it = 0; it < niter; ++it) {
    if (it < niter-2)      asm volatile("s_waitcnt vmcnt(6)" ::: "memory");
    else if (it < niter-1) asm volatile("s_waitcnt vmcnt(3)" ::: "memory");
    else                   asm volatile("s_waitcnt vmcnt(0)" ::: "memory");
    __builtin_amdgcn_s_barrier();
    __builtin_amdgcn_sched_barrier(0);
    s16x8 a[4], b[4];
    #pragma unroll
    for (int i=0;i<4;i++) a[i] = *(const s16x8*)(As + cur*ABUF + (ra + i*16)*32 + sw);
    #pragma unroll
    for (int j=0;j<4;j++) b[j] = *(const s16x8*)(Bs + cur*BBUF + (rb + j*16)*32 + sw);
    #pragma unroll
    for (int i=0;i<4;i++)
      #pragma unroll
      for (int j=0;j<4;j++)
        acc[i][j] = __builtin_amdgcn_mfma_f32_16x16x32_bf16(a[i], b[j], acc[i][j], 0, 0, 0);
    __builtin_amdgcn_sched_barrier(0);
    __builtin_amdgcn_s_barrier();
    if (it + 3 < niter) {             // re-stage into the buffer just freed
      const int k0 = (it+3)*32;
      gld16(gA0 + k0, lA0 + cur*ABUF);
      gld16(gA1 + k0, lA1 + cur*ABUF);
      gld16(gB0 + k0, lB0 + cur*BBUF);
    }
    cur = (cur == 2) ? 0 : cur + 1;
  }
}

// ---------------------------------------------------------------------------
// K3: scores, operand-swapped (A=K 256-tile, B=Q 128-tile), packed 8B stores.
// 1-D grid + XCD-chunked swizzle, row-block (y) INNERMOST within a chunk so
// the 24 row-blocks sharing one K-panel land on one XCD's L2 (T1 mechanism).
// grid = 12*24*nz, divisible by 8 for nz in {2,4} -> bijective.
// ---------------------------------------------------------------------------
__global__ __launch_bounds__(512) void scores_kernel(
    const u16* __restrict__ Qf, const u16* __restrict__ Kf,
    u16* __restrict__ P, float* __restrict__ lbuf, int bh0)
{
  __shared__ __align__(16) u16 As[3*ABUF];   // 48 KB
  __shared__ __align__(16) u16 Bs[3*BBUF];   // 24 KB
  const int tid = threadIdx.x, w = tid>>6, l = tid&63;
  const int cpx = gridDim.x >> 3;
  const int swz = (blockIdx.x & 7)*cpx + (blockIdx.x >> 3);
  const int yb  = swz % 24;                  // row-block, innermost
  const int g   = swz / 24;
  const int xb  = g % 12;                    // gcol-block
  const int z   = g / 12;
  const int bh = bh0 + z;
  const int gcol0 = xb*256, row0 = yb*128;
  const u16* Ag = Kf + ((size_t)bh*TP + gcol0)*SQK;   // A = K
  const u16* Bg = Qf + ((size_t)bh*TP + row0)*SQK;    // B = Q

  f32x4 acc[4][4];
  #pragma unroll
  for (int i=0;i<4;i++)
    #pragma unroll
    for (int j=0;j<4;j++) acc[i][j] = (f32x4){0.f,0.f,0.f,0.f};

  gemm_core(Ag, Bg, SQK, SQK, 9, As, Bs, acc, w, l, tid);

  const float scale = 0.062017367294604234f;   // 1/sqrt(260)
  const int m = l & 15, q = l >> 4;
  u16* Pz = P + (size_t)z*TP*TP;
  float* lrow = lbuf + (size_t)bh*TP;

  float rsum[4] = {0.f,0.f,0.f,0.f};
  #pragma unroll
  for (int i=0;i<4;i++){
    const int gcb = gcol0 + (w&3)*64 + i*16 + q*4;   // 4 consecutive gcols
    #pragma unroll
    for (int j=0;j<4;j++){
      const int grow = row0 + (w>>2)*64 + j*16 + m;
      float pv[4];
      #pragma unroll
      for (int reg=0; reg<4; reg++){
        float v = __expf(acc[i][j][reg]*scale);
        if (gcb + reg >= T_) v = 0.f;
        pv[reg] = v; rsum[j] += v;
      }
      const u32 lo = (u32)f2bf(pv[0]) | ((u32)f2bf(pv[1])<<16);
      const u32 hi = (u32)f2bf(pv[2]) | ((u32)f2bf(pv[3])<<16);
      *(uint2*)(Pz + (size_t)grow*TP + gcb) = make_uint2(lo, hi);
    }
  }
  #pragma unroll
  for (int j=0;j<4;j++){
    float r = rsum[j];
    r += __shfl_xor(r, 16);
    r += __shfl_xor(r, 32);
    if (q == 0) atomicAdd(&lrow[row0 + (w>>2)*64 + j*16 + m], r);
  }
}

// ---------------------------------------------------------------------------
// K4: O = (P~ * V) / l -> Og bf16 [bh][t][gcol] (coalesced).
// 1-D grid + XCD-chunked swizzle, col-block (y) INNERMOST: the 9 col-blocks
// sharing one 1.5MB P-row-panel run on one XCD -> panel fetched once into
// that L2 (round-9 FETCH was 183MB vs 103MB payload from cross-XCD re-reads).
// grid = 12*9*nz, divisible by 8 for nz in {2,4} -> bijective.
// ---------------------------------------------------------------------------
__global__ __launch_bounds__(512) void pv_kernel(
    const u16* __restrict__ P, const u16* __restrict__ Vt,
    const float* __restrict__ lbuf, u16* __restrict__ Og, int bh0)
{
  __shared__ __align__(16) u16 As[3*ABUF];
  __shared__ __align__(16) u16 Bs[3*BBUF];
  const int tid = threadIdx.x, w = tid>>6, l = tid&63;
  const int cpx = gridDim.x >> 3;
  const int swz = (blockIdx.x & 7)*cpx + (blockIdx.x >> 3);
  const int yb  = swz % 9;                   // col-block, innermost
  const int g   = swz / 9;
  const int xb  = g % 12;                    // row-block
  const int z   = g / 12;
  const int bh = bh0 + z;
  const int row0 = xb*256, col0 = yb*128;
  const u16* Ag = P + (size_t)z*TP*TP + (size_t)row0*TP;
  const u16* Bg = Vt + ((size_t)bh*VTROWS + col0)*TK;

  f32x4 acc[4][4];
  #pragma unroll
  for (int i=0;i<4;i++)
    #pragma unroll
    for (int j=0;j<4;j++) acc[i][j] = (f32x4){0.f,0.f,0.f,0.f};

  gemm_core(Ag, Bg, TP, TK, 94, As, Bs, acc, w, l, tid);

  const int m = l & 15, q = l >> 4;
  const float* lrow = lbuf + (size_t)bh*TP;

  #pragma unroll
  for (int i=0;i<4;i++){
    #pragma unroll
    for (int reg=0; reg<4; reg++){
      const int grow = row0 + (w&3)*64 + i*16 + q*4 + reg;
      if (grow >= T_) continue;
      const float linv = 1.0f / lrow[grow];
      u16* orow = Og + ((size_t)bh*T_ + grow)*EF;
      #pragma unroll
      for (int j=0;j<4;j++){
        const int gcol = col0 + (w>>2)*64 + j*16 + m;
        if (gcol < EF)
          orow[gcol] = f2bf(acc[i][j][reg]*linv);
      }
    }
  }
}

// ---------------------------------------------------------------------------
// K5: final 1x1 conv (64x64) + PReLU + LN over C + residual, MFMA-style.
// Og gcol = f*16+e -> fragment gather is one aligned 16B load.
// ---------------------------------------------------------------------------
__global__ __launch_bounds__(256) void outp_kernel(
    const u16* __restrict__ Og, const float* __restrict__ x,
    const float* __restrict__ Wp, const float* __restrict__ bp, const float* __restrict__ ap,
    const float* __restrict__ gp, const float* __restrict__ btep,
    float* __restrict__ out)
{
  __shared__ __align__(16) u16 wlds[2*64*64];   // Whi | Wlo, swizzled (16 KB)
  __shared__ float prm[193];
  const int tid = threadIdx.x;
  for (int i = tid; i < 4096; i += 256){
    const int row = i >> 6, c = i & 63;
    const float w = Wp[row*64 + c];
    const u16 hi = f2bf(w);
    const u16 lo = f2bf(w - bf2f(hi));
    const int byo = ((row<<7) + (c<<1)) ^ ((row&7)<<4);
    *(u16*)((char*)wlds + byo)        = hi;
    *(u16*)((char*)wlds + 8192 + byo) = lo;
  }
  if (tid < 193) {
    float v;
    if      (tid < 64)  v = bp[tid];
    else if (tid < 128) v = gp[tid-64];
    else if (tid < 192) v = btep[tid-128];
    else                v = ap[0];
    prm[tid] = v;
  }
  __syncthreads();

  const int wv_ = tid >> 6, l = tid & 63;
  const int lm = l & 15, lq = l >> 4;
  const int p0 = blockIdx.x*128 + wv_*32;

  int bb[2], rr[2], tt[2], ff[2]; bool ok[2];
  #pragma unroll
  for (int nt=0; nt<2; nt++){
    int p = p0 + nt*16 + lm;
    ok[nt] = (p < NPT);
    if (p >= NPT) p = NPT-1;
    bb[nt] = (p >= TF_) ? 1 : 0;
    rr[nt] = p - bb[nt]*TF_;
    tt[nt] = (int)(((unsigned long long)rr[nt] * 516223ULL) >> 25);   // r/65 exact
    ff[nt] = rr[nt] - tt[nt]*65;
  }

  f32x4 acc[4][2];
  #pragma unroll
  for (int i=0;i<4;i++){
    acc[i][0]=(f32x4){0.f,0.f,0.f,0.f};
    acc[i][1]=(f32x4){0.f,0.f,0.f,0.f};
  }

  #pragma unroll
  for (int ks=0; ks<2; ks++){
    const int c0 = ks*32 + lq*8;        // 8 input channels, h uniform in chunk
    const int h  = c0 >> 4;
    const int e0 = c0 & 15;
    s16x8 xf[2];
    #pragma unroll
    for (int nt=0; nt<2; nt++){
      const u16* base = Og + ((size_t)(bb[nt]*4 + h)*T_ + tt[nt])*EF + ff[nt]*16 + e0;
      xf[nt] = *(const s16x8*)base;     // 16B aligned
    }
    #pragma unroll
    for (int mt=0; mt<4; mt++){
      const int rowb = mt*16 + lm;
      const int byo = ((rowb<<7) + (c0<<1)) ^ ((rowb&7)<<4);
      const s16x8 whi = *(const s16x8*)((const char*)wlds + byo);
      const s16x8 wlo = *(const s16x8*)((const char*)wlds + 8192 + byo);
      #pragma unroll
      for (int nt=0; nt<2; nt++){
        acc[mt][nt] = __builtin_amdgcn_mfma_f32_16x16x32_bf16(whi, xf[nt], acc[mt][nt], 0,0,0);
        acc[mt][nt] = __builtin_amdgcn_mfma_f32_16x16x32_bf16(wlo, xf[nt], acc[mt][nt], 0,0,0);
      }
    }
  }

  const float apv = prm[192];
  #pragma unroll
  for (int nt=0; nt<2; nt++){
    if (!ok[nt]) continue;              // uniform across {l, l^16, l^32, l^48}
    const int b = bb[nt], r = rr[nt];
    float v[4][4]; float s1 = 0.f, s2 = 0.f;
    #pragma unroll
    for (int mt=0; mt<4; mt++){
      #pragma unroll
      for (int reg=0; reg<4; reg++){
        const int o = mt*16 + lq*4 + reg;
        float a = acc[mt][nt][reg] + prm[o];
        a = (a >= 0.f) ? a : apv*a;
        v[mt][reg] = a; s1 += a; s2 = fmaf(a,a,s2);
      }
    }
    s1 += __shfl_xor(s1,16); s1 += __shfl_xor(s1,32);
    s2 += __shfl_xor(s2,16); s2 += __shfl_xor(s2,32);
    const float mu = s1*(1.f/64.f);
    const float var = s2*(1.f/64.f) - mu*mu;
    const float rs = rsqrtf(var + 1e-5f);
    const float* xb = x + (size_t)b*C_*TF_ + r;
    float* yb = out + (size_t)b*C_*TF_ + r;
    #pragma unroll
    for (int mt=0; mt<4; mt++){
      #pragma unroll
      for (int reg=0; reg<4; reg++){
        const int o = mt*16 + lq*4 + reg;
        yb[(size_t)o*TF_] = fmaf((v[mt][reg]-mu)*rs, prm[64+o], prm[128+o]) + xb[(size_t)o*TF_];
      }
    }
  }
}

// ---------------------------------------------------------------------------
extern "C" void kernel_launch(void* const* d_in, const int* in_sizes, int n_in,
                              void* d_out, int out_size, void* d_ws, size_t ws_size,
                              hipStream_t stream)
{
  const float* x    = (const float*)d_in[0];
  const float* Wq   = (const float*)d_in[1];
  const float* bq   = (const float*)d_in[2];
  const float* aq   = (const float*)d_in[3];
  const float* gq   = (const float*)d_in[4];
  const float* bteq = (const float*)d_in[5];
  const float* Wk   = (const float*)d_in[6];
  const float* bk   = (const float*)d_in[7];
  const float* ak   = (const float*)d_in[8];
  const float* gk   = (const float*)d_in[9];
  const float* btek = (const float*)d_in[10];
  const float* Wv   = (const float*)d_in[11];
  const float* bv   = (const float*)d_in[12];
  const float* av   = (const float*)d_in[13];
  const float* gv   = (const float*)d_in[14];
  const float* btev = (const float*)d_in[15];
  const float* Wp   = (const float*)d_in[16];
  const float* bp   = (const float*)d_in[17];
  const float* ap   = (const float*)d_in[18];
  const float* gp   = (const float*)d_in[19];
  const float* btep = (const float*)d_in[20];

  // workspace layout (bytes):
  //   Qf   bf16 [8][3072][328]   @ 0            (16,121,856)
  //   Kf   bf16 [8][3072][328]   @ 16,121,856   (16,121,856)
  //   Vf   bf16 [8][3000][1040]  @ 32,243,712   (49,920,000)  -- dead after vtrans
  //   Og   bf16 [8][3000][1040]  @ 32,243,712   (49,920,000)  -- overlays Vf
  //   Vt   bf16 [8][1152][3008]  @ 82,163,712   (55,443,456)
  // z=4 layout (needs 213,202,944 B):
  //   lbuf f32  [8][3072]        @ 137,607,168  (98,304)
  //   P    bf16 [4][3072][3072]  @ 137,705,472  (75,497,472)
  // z=2 fallback (old layout, 175,454,208 B):
  //   P    bf16 [2][3072][3072]  @ 137,607,168  (37,748,736)
  //   lbuf f32  [8][3072]        @ 175,355,904  (98,304)
  char* ws = (char*)d_ws;
  u16*   Qf   = (u16*)(ws + 0);
  u16*   Kf   = (u16*)(ws + 16121856);
  u16*   Vf   = (u16*)(ws + 32243712);
  u16*   Og   = (u16*)(ws + 32243712);
  u16*   Vt   = (u16*)(ws + 82163712);
  const bool z4 = (ws_size >= (size_t)213202944);
  u16*   P;
  float* lbuf;
  if (z4) { lbuf = (float*)(ws + 137607168); P = (u16*)(ws + 137705472); }
  else    { P = (u16*)(ws + 137607168);      lbuf = (float*)(ws + 175355904); }
  float* out  = (float*)d_out;

  qkv_kernel<<<dim3((NPT+127)/128), dim3(256), 0, stream>>>(
      x, Wq,bq,aq,gq,bteq, Wk,bk,ak,gk,btek, Wv,bv,av,gv,btev, Qf,Kf,Vf, lbuf);
  vtrans_kernel<<<dim3(47, 17, 8), dim3(256), 0, stream>>>(Vf, Vt);
  if (z4) {
    for (int c = 0; c < 2; ++c) {
      scores_kernel<<<dim3(12*24*4), dim3(512), 0, stream>>>(Qf, Kf, P, lbuf, c*4);
      pv_kernel<<<dim3(12*9*4), dim3(512), 0, stream>>>(P, Vt, lbuf, Og, c*4);
    }
  } else {
    for (int c = 0; c < 4; ++c) {
      scores_kernel<<<dim3(12*24*2), dim3(512), 0, stream>>>(Qf, Kf, P, lbuf, c*2);
      pv_kernel<<<dim3(12*9*2), dim3(512), 0, stream>>>(P, Vt, lbuf, Og, c*2);
    }
  }
  outp_kernel<<<dim3((NPT+127)/128), dim3(256), 0, stream>>>(
      Og, x, Wp,bp,ap,gp,btep, out);
}